// Round 5
// baseline (55.211 us; speedup 1.0000x reference)
//
#include <hip/hip_runtime.h>

#define SL 10
#define NI 128

typedef float f32x4 __attribute__((ext_vector_type(4)));
typedef unsigned int u32;
typedef u32 u32x4 __attribute__((ext_vector_type(4)));
typedef _Float16 h8 __attribute__((ext_vector_type(8)));
typedef _Float16 h4 __attribute__((ext_vector_type(4)));

__device__ __forceinline__ f32x4 MFH(h8 a, h8 b, f32x4 c){
  return __builtin_amdgcn_mfma_f32_16x16x32_f16(a, b, c, 0, 0, 0);
}
__device__ __forceinline__ float sigf(float x){ return __fdividef(1.f, 1.f + __expf(-x)); }
__device__ __forceinline__ float tanhf2(float x){ return __fdividef(2.f, 1.f + __expf(-2.f*x)) - 1.f; }

__device__ __forceinline__ h8 to_h8(float4 a, float4 b){
  h8 r;
  r[0]=(_Float16)a.x; r[1]=(_Float16)a.y; r[2]=(_Float16)a.z; r[3]=(_Float16)a.w;
  r[4]=(_Float16)b.x; r[5]=(_Float16)b.y; r[6]=(_Float16)b.z; r[7]=(_Float16)b.w;
  return r;
}

// One wave (64 threads) per 16 batch rows, zero barriers.
// x path: COALESCED loads (each instr = 2 rows x 512B dense spans), f32->f16 cvt,
// wave-private LDS transpose (double-buffered by t parity, in-order DS pipe, no
// s_barrier), ds_read_b128 -> B fragments.
//   A = weights (gate-permuted rows: tile nt, A-row lr -> gate (lr&3)*20+(lr>>2)+nt*4),
//   B = x/h (col = batch row lr). C-reg i of lane (lr,lg) = gate type i of unit
//   nt*4+lg for batch col lr -> fp32 gate math fully in-register.
//   h exchange via 2KB wave-private LDS (stride 33), no barrier.
// LDS fragment tile layout (bytes): XT[par][ks][c][16] with c = row*4 + lg;
//   read: lane(lr,lg), frag ks at par*4096 + ks*1024 + (lr*4+lg)*16  (b128)
//   write: lane holding row=j*2+rh, k=kq*4.. : ks=kq>>3, lgw=(kq>>1)&3, sub=kq&1
//          at par*4096 + ks*1024 + j*128 + rh*64 + lgw*16 + sub*8      (b64)
__global__ __launch_bounds__(64, 2) void bilstm_kernel(
    const float* __restrict__ x,
    const float* __restrict__ Wih_f, const float* __restrict__ Whh_f,
    const float* __restrict__ bih_f, const float* __restrict__ bhh_f,
    const float* __restrict__ Wih_b,
    const float* __restrict__ bih_b, const float* __restrict__ bhh_b,
    float* __restrict__ out)
{
  __shared__ __attribute__((aligned(16))) char XT[8192];  // 2 x 4KB frag tiles
  __shared__ u32 HB[16*33];                               // h exchange, stride 33

  const int l  = threadIdx.x;
  const int lr = l & 15;
  const int lg = l >> 4;
  const int rh = l >> 5;        // row-pair half for coalesced loads
  const int kq = l & 31;        // float4 index within a row
  const long b0 = (long)blockIdx.x * 16;
  const int gb = (lr&3)*20 + (lr>>2);

  for(int i=l;i<16*33;i+=64) HB[i]=0;

  // per-lane write address (invariant part) for the LDS transpose
  const int woff = ((kq>>3)<<10) + rh*64 + (((kq>>1)&3)<<4) + ((kq&1)<<3);
  // per-lane read base
  const int roff = (lr*4+lg)*16;

  // coalesced x source: lane reads row (b0 + 2j + rh), 16B at k=kq*4
  const float* xsrc = x + (b0 + rh)*(long)(SL*NI) + kq*4;

  // ---- prologue: issue t=0 loads ----
  float4 buf[8];
  #pragma unroll
  for(int j=0;j<8;j++) buf[j] = *(const float4*)(xsrc + j*2*SL*NI);

  // ---- W_ih_f fragments (f16), register-resident ----
  h8 WIH[20];
  #pragma unroll
  for(int p=0;p<20;p++){
    const int nt=p>>2, ks=p&3;
    const float* s = Wih_f + (gb+nt*4)*NI + ks*32 + lg*8;
    WIH[p] = to_h8(*(const float4*)s, *(const float4*)(s+4));
  }
  // ---- W_hh_f fragments (K=20 zero-padded to 32) ----
  h8 WHH[5];
  #pragma unroll
  for(int nt=0;nt<5;nt++){
    h8 r;
    #pragma unroll
    for(int j=0;j<8;j++){
      const int k = lg*8+j;
      r[j] = (_Float16)((k<20) ? Whh_f[(gb+nt*4)*20+k] : 0.f);
    }
    WHH[nt]=r;
  }
  f32x4 biasv[5];
  #pragma unroll
  for(int nt=0;nt<5;nt++)
    #pragma unroll
    for(int ty=0;ty<4;ty++)
      biasv[nt][ty] = bih_f[ty*20+nt*4+lg] + bhh_f[ty*20+nt*4+lg];

  float cst[5]={0.f,0.f,0.f,0.f,0.f};
  h8 bx[4];
  f32x4 acc[5];

  #pragma unroll
  for(int t=0;t<SL;t++){
    const int par = (t&1)<<12;
    // ---- cvt f32->f16 and transpose-write x_t into LDS (same-wave, no barrier)
    #pragma unroll
    for(int j=0;j<8;j++){
      float4 v = buf[j];
      h4 hv; hv[0]=(_Float16)v.x; hv[1]=(_Float16)v.y; hv[2]=(_Float16)v.z; hv[3]=(_Float16)v.w;
      *(h4*)(XT + par + woff + j*128) = hv;
    }
    // ---- issue coalesced loads for t+1 (fly under MFMA+gates) ----
    if(t+1<SL){
      #pragma unroll
      for(int j=0;j<8;j++) buf[j] = *(const float4*)(xsrc + j*2*SL*NI + (t+1)*NI);
    }
    // ---- read B fragments (in-order DS pipe guarantees write->read) ----
    #pragma unroll
    for(int ks=0;ks<4;ks++) bx[ks] = *(const h8*)(XT + par + (ks<<10) + roff);
    // ---- h_{t-1} read (wave-coherent LDS) ----
    u32x4 hb0, hb1;
    if(t>0){
      const u32* hp = HB + lr*33 + lg*8;
      hb0=*(const u32x4*)hp; hb1=*(const u32x4*)(hp+4);
    }
    #pragma unroll
    for(int nt=0;nt<5;nt++) acc[nt]=biasv[nt];
    // ---- projection: 20 MFMAs ----
    #pragma unroll
    for(int ks=0;ks<4;ks++)
      #pragma unroll
      for(int nt=0;nt<5;nt++)
        acc[nt]=MFH(WIH[nt*4+ks], bx[ks], acc[nt]);
    // ---- recurrence: 10 MFMAs (h 2-term f16) ----
    if(t>0){
      u32x4 hh, hl;
      hh[0]=(hb0[0]>>16)|(hb0[1]&0xffff0000u);
      hh[1]=(hb0[2]>>16)|(hb0[3]&0xffff0000u);
      hh[2]=(hb1[0]>>16)|(hb1[1]&0xffff0000u);
      hh[3]=(hb1[2]>>16)|(hb1[3]&0xffff0000u);
      hl[0]=(hb0[0]&0xffffu)|(hb0[1]<<16);
      hl[1]=(hb0[2]&0xffffu)|(hb0[3]<<16);
      hl[2]=(hb1[0]&0xffffu)|(hb1[1]<<16);
      hl[3]=(hb1[2]&0xffffu)|(hb1[3]<<16);
      h8 fh=__builtin_bit_cast(h8,hh), fl=__builtin_bit_cast(h8,hl);
      #pragma unroll
      for(int nt=0;nt<5;nt++){
        acc[nt]=MFH(WHH[nt], fh, acc[nt]);
        acc[nt]=MFH(WHH[nt], fl, acc[nt]);
      }
    }
    // ---- in-register fp32 gate math ----
    #pragma unroll
    for(int nt=0;nt<5;nt++){
      float ig=sigf(acc[nt][0]);
      float fg=sigf(acc[nt][1]);
      float gg=tanhf2(acc[nt][2]);
      float og=sigf(acc[nt][3]);
      cst[nt]=fg*cst[nt]+ig*gg;
      float hv=og*tanhf2(cst[nt]);
      if(t==SL-1){
        out[(b0+lr)*40 + nt*4+lg] = hv;
      } else {
        _Float16 hh16=(_Float16)hv;
        _Float16 hl16=(_Float16)(hv-(float)hh16);
        HB[lr*33 + nt*4+lg] = ((u32)__builtin_bit_cast(unsigned short,hh16)<<16)
                              | (u32)__builtin_bit_cast(unsigned short,hl16);
      }
    }
  }

  // ---- backward direction: one step, h0=c0=0, bx still holds x[t=9] frags ----
  f32x4 a2[5];
  #pragma unroll
  for(int nt=0;nt<5;nt++)
    #pragma unroll
    for(int ty=0;ty<4;ty++)
      a2[nt][ty] = bih_b[ty*20+nt*4+lg] + bhh_b[ty*20+nt*4+lg];
  #pragma unroll
  for(int ks=0;ks<4;ks++){
    #pragma unroll
    for(int nt=0;nt<5;nt++){
      const float* s = Wih_b + (gb+nt*4)*NI + ks*32 + lg*8;
      a2[nt]=MFH(to_h8(*(const float4*)s, *(const float4*)(s+4)), bx[ks], a2[nt]);
    }
  }
  #pragma unroll
  for(int nt=0;nt<5;nt++){
    float ig=sigf(a2[nt][0]);
    float gg=tanhf2(a2[nt][2]);
    float og=sigf(a2[nt][3]);
    out[(b0+lr)*40 + 20 + nt*4+lg] = og*tanhf2(ig*gg);   // c = i*g (f-gate hits c0=0)
  }
}

extern "C" void kernel_launch(void* const* d_in, const int* in_sizes, int n_in,
                              void* d_out, int out_size, void* d_ws, size_t ws_size,
                              hipStream_t stream) {
  const float* x     = (const float*)d_in[0];
  const float* Wih_f = (const float*)d_in[1];
  const float* Whh_f = (const float*)d_in[2];
  const float* bih_f = (const float*)d_in[3];
  const float* bhh_f = (const float*)d_in[4];
  const float* Wih_b = (const float*)d_in[5];
  // d_in[6] = W_hh_b: provably unused (hs_b[0] has h0 = 0)
  const float* bih_b = (const float*)d_in[7];
  const float* bhh_b = (const float*)d_in[8];
  float* out = (float*)d_out;
  bilstm_kernel<<<dim3(2048), dim3(64), 0, stream>>>(
      x, Wih_f, Whh_f, bih_f, bhh_f, Wih_b, bih_b, bhh_b, out);
}